// Round 1
// baseline (913.290 us; speedup 1.0000x reference)
//
#include <hip/hip_runtime.h>
#include <cstdint>
#include <cstddef>

#define K_PAD 4128  // 4097 padded up to a multiple of 32 (zeros contribute 0)

typedef __bf16 bf16x8 __attribute__((ext_vector_type(8)));
typedef float f32x4 __attribute__((ext_vector_type(4)));

__device__ __forceinline__ unsigned short f2bf(float f) {
  // round-to-nearest-even fp32 -> bf16
  unsigned int u = __float_as_uint(f);
  u = (u + 0x7fffu + ((u >> 16) & 1u)) >> 16;
  return (unsigned short)u;
}

__device__ __forceinline__ void gload_lds16(const void* g, void* l) {
  __builtin_amdgcn_global_load_lds((const __attribute__((address_space(1))) void*)g,
                                   (__attribute__((address_space(3))) void*)l,
                                   16, 0, 0);
}

// x (8192x4096 f32) -> xa (8192x4128 bf16): cols 0..4095 = x, col 4096 = 1.0, 4097.. = 0
__global__ void k_xaug(const float* __restrict__ x, unsigned short* __restrict__ xa) {
  const int row = blockIdx.x;
  const int t = threadIdx.x;
  const float4* xr = (const float4*)(x + (size_t)row * 4096);
  unsigned short* out = xa + (size_t)row * K_PAD;
#pragma unroll
  for (int i = 0; i < 4; ++i) {
    const int g = t + i * 256;  // float4 group within row, 0..1023
    float4 v = xr[g];
    ushort4 o;
    o.x = f2bf(v.x); o.y = f2bf(v.y); o.z = f2bf(v.z); o.w = f2bf(v.w);
    *(ushort4*)(out + g * 4) = o;
  }
  if (t < 32) out[4096 + t] = (t == 0) ? (unsigned short)0x3F80 : (unsigned short)0;
}

// weights = q_mu + exp(q_ls)*eps -> bf16 (4096x4128, padded cols zero)
// kl summed elementwise, one atomicAdd per block
__global__ void k_wkl(const float* __restrict__ q_mu, const float* __restrict__ q_ls,
                      const float* __restrict__ p_mu, const float* __restrict__ eps,
                      const float* __restrict__ p_ls, unsigned short* __restrict__ w,
                      float* __restrict__ kl_out) {
  const int row = blockIdx.x;   // 4096 rows
  const int t = threadIdx.x;    // 256 threads
  const float pls = p_ls[0];
  const float inv2ps2 = 0.5f * __expf(-2.0f * pls);  // 1/(2*p_sigma^2)
  const size_t base = (size_t)row * 4097;
  unsigned short* wr = w + (size_t)row * K_PAD;
  float kl = 0.f;
#pragma unroll 1
  for (int i = 0; i < 17; ++i) {
    const int c = t + i * 256;  // 0..4351 range; guard below
    if (c < 4097) {
      float qm = q_mu[base + c];
      float ql = q_ls[base + c];
      float qs = __expf(ql);
      float e  = eps[base + c];
      float pm = p_mu[base + c];
      float d = pm - qm;
      kl += (pls - ql) - 0.5f + (qs * qs + d * d) * inv2ps2;
      wr[c] = f2bf(__fmaf_rn(qs, e, qm));
    } else if (c < K_PAD) {
      wr[c] = 0;
    }
  }
#pragma unroll
  for (int off = 32; off > 0; off >>= 1) kl += __shfl_down(kl, off, 64);
  __shared__ float part[4];
  const int wave = t >> 6, lane = t & 63;
  if (lane == 0) part[wave] = kl;
  __syncthreads();
  if (t == 0) atomicAdd(kl_out, part[0] + part[1] + part[2] + part[3]);
}

// C(8192x4096 f32) = A(8192xK_PAD bf16) * B^T, B = (4096xK_PAD bf16), both K-contiguous.
// 128x128 tile, BK=32, 4 waves of 64x64, mfma_f32_16x16x32_bf16, global_load_lds staging.
__global__ __launch_bounds__(256) void k_gemm(const unsigned short* __restrict__ A,
                                              const unsigned short* __restrict__ Bm,
                                              float* __restrict__ C) {
  __shared__ unsigned short As[128 * 32];
  __shared__ unsigned short Bs[128 * 32];
  const int t = threadIdx.x;
  const int wave = t >> 6;
  const int lane = t & 63;
  const int wm = wave >> 1;     // 2x2 wave grid
  const int wn = wave & 1;
  const int rowBase = blockIdx.y * 128;
  const int colBase = blockIdx.x * 128;

  const int fr = lane & 15;        // fragment row/col within 16
  const int fk = (lane >> 4) * 8;  // k offset (8 consecutive bf16 per lane)

  f32x4 acc[4][4] = {};

  const unsigned short* Abase = A + (size_t)rowBase * K_PAD;
  const unsigned short* Bbase = Bm + (size_t)colBase * K_PAD;

  // staging coords: thread t covers 16B at tile-flat idx (s*256+t)*8 bf16
  const int r0 = t >> 2;          // row within tile for s=0
  const int kc = (t & 3) * 8;     // k column (bf16) of the 16B chunk

  for (int k0 = 0; k0 < K_PAD; k0 += 32) {
#pragma unroll
    for (int s = 0; s < 2; ++s) {
      const int r = s * 64 + r0;
      const int ldsoff = (s * 256 + wave * 64) * 8;  // wave-uniform base (elements)
      gload_lds16(Abase + (size_t)r * K_PAD + k0 + kc, As + ldsoff);
      gload_lds16(Bbase + (size_t)r * K_PAD + k0 + kc, Bs + ldsoff);
    }
    __syncthreads();
    bf16x8 af[4], bfv[4];
#pragma unroll
    for (int i = 0; i < 4; ++i) {
      af[i]  = *(const bf16x8*)&As[(wm * 64 + i * 16 + fr) * 32 + fk];
      bfv[i] = *(const bf16x8*)&Bs[(wn * 64 + i * 16 + fr) * 32 + fk];
    }
#pragma unroll
    for (int i = 0; i < 4; ++i)
#pragma unroll
      for (int j = 0; j < 4; ++j)
        acc[i][j] = __builtin_amdgcn_mfma_f32_16x16x32_bf16(af[i], bfv[j], acc[i][j], 0, 0, 0);
    __syncthreads();
  }

  // C/D layout: col = lane&15, row = (lane>>4)*4 + reg
  const int cr = (lane >> 4) * 4;
  const int cc = lane & 15;
#pragma unroll
  for (int i = 0; i < 4; ++i) {
#pragma unroll
    for (int j = 0; j < 4; ++j) {
      const int col = colBase + wn * 64 + j * 16 + cc;
#pragma unroll
      for (int r = 0; r < 4; ++r) {
        const int row = rowBase + wm * 64 + i * 16 + cr + r;
        C[(size_t)row * 4096 + col] = acc[i][j][r];
      }
    }
  }
}

extern "C" void kernel_launch(void* const* d_in, const int* in_sizes, int n_in,
                              void* d_out, int out_size, void* d_ws, size_t ws_size,
                              hipStream_t stream) {
  const float* x      = (const float*)d_in[0];
  const float* p_ls   = (const float*)d_in[1];
  const float* q_mu   = (const float*)d_in[2];
  const float* q_lsig = (const float*)d_in[3];
  const float* p_mu   = (const float*)d_in[4];
  const float* eps    = (const float*)d_in[5];
  float* out = (float*)d_out;
  float* kl_out = out + (size_t)8192 * 4096;

  // ws layout: x_aug bf16 (8192*4128 = 67.6MB), weights bf16 (4096*4128 = 33.8MB)
  unsigned short* xa   = (unsigned short*)d_ws;
  unsigned short* wmat = xa + (size_t)8192 * K_PAD;

  hipMemsetAsync(kl_out, 0, sizeof(float), stream);
  k_xaug<<<8192, 256, 0, stream>>>(x, xa);
  k_wkl<<<4096, 256, 0, stream>>>(q_mu, q_lsig, p_mu, eps, p_ls, wmat, kl_out);
  k_gemm<<<dim3(32, 64), 256, 0, stream>>>(xa, wmat, out);
}

// Round 2
// 900.227 us; speedup vs baseline: 1.0145x; 1.0145x over previous
//
#include <hip/hip_runtime.h>
#include <cstdint>
#include <cstddef>

#define K_PAD 4128  // 4097 padded up to a multiple of 32 (zeros contribute 0)

typedef __bf16 bf16x8 __attribute__((ext_vector_type(8)));
typedef float f32x4 __attribute__((ext_vector_type(4)));

__device__ __forceinline__ unsigned short f2bf(float f) {
  // round-to-nearest-even fp32 -> bf16
  unsigned int u = __float_as_uint(f);
  u = (u + 0x7fffu + ((u >> 16) & 1u)) >> 16;
  return (unsigned short)u;
}

__device__ __forceinline__ void gload_lds16(const void* g, void* l) {
  __builtin_amdgcn_global_load_lds((const __attribute__((address_space(1))) void*)g,
                                   (__attribute__((address_space(3))) void*)l,
                                   16, 0, 0);
}

// x (8192x4096 f32) -> xa (8192x4128 bf16): cols 0..4095 = x, col 4096 = 1.0, 4097.. = 0
__global__ void k_xaug(const float* __restrict__ x, unsigned short* __restrict__ xa) {
  const int row = blockIdx.x;
  const int t = threadIdx.x;
  const float4* xr = (const float4*)(x + (size_t)row * 4096);
  unsigned short* out = xa + (size_t)row * K_PAD;
#pragma unroll
  for (int i = 0; i < 4; ++i) {
    const int g = t + i * 256;  // float4 group within row, 0..1023
    float4 v = xr[g];
    ushort4 o;
    o.x = f2bf(v.x); o.y = f2bf(v.y); o.z = f2bf(v.z); o.w = f2bf(v.w);
    *(ushort4*)(out + g * 4) = o;
  }
  if (t < 32) out[4096 + t] = (t == 0) ? (unsigned short)0x3F80 : (unsigned short)0;
}

// weights = q_mu + exp(q_ls)*eps -> bf16 (4096x4128, padded cols zero)
// kl summed elementwise, one atomicAdd per block. float4-vectorized main body.
__global__ void k_wkl(const float* __restrict__ q_mu, const float* __restrict__ q_ls,
                      const float* __restrict__ p_mu, const float* __restrict__ eps,
                      const float* __restrict__ p_ls, unsigned short* __restrict__ w,
                      float* __restrict__ kl_out) {
  const int row = blockIdx.x;   // 4096 rows
  const int t = threadIdx.x;    // 256 threads
  const float pls = p_ls[0];
  const float inv2ps2 = 0.5f * __expf(-2.0f * pls);  // 1/(2*p_sigma^2)
  const size_t base = (size_t)row * 4097;
  unsigned short* wr = w + (size_t)row * K_PAD;
  float kl = 0.f;
  const float4* qm4 = (const float4*)(q_mu + base);
  const float4* ql4 = (const float4*)(q_ls + base);
  const float4* pm4 = (const float4*)(p_mu + base);
  const float4* ep4 = (const float4*)(eps + base);
  // NOTE: base = row*4097 is only 4B-aligned... row*4097*4 bytes; 4097 odd ->
  // alignment of float4 loads not guaranteed. Use vector loads only when the
  // base is 16B aligned; rows where (row*4097)%4 != 0 fall back to scalar.
  if ((((size_t)row * 4097) & 3) == 0) {
#pragma unroll 1
    for (int i = 0; i < 4; ++i) {
      const int g = t + i * 256;  // float4 group 0..1023 covers cols 0..4095
      float4 qm = qm4[g], ql = ql4[g], pm = pm4[g], ep = ep4[g];
      float kls = 0.f;
      ushort4 o;
      {
        float qs = __expf(ql.x); float d = pm.x - qm.x;
        kls += (pls - ql.x) - 0.5f + (qs * qs + d * d) * inv2ps2;
        o.x = f2bf(__fmaf_rn(qs, ep.x, qm.x));
      }
      {
        float qs = __expf(ql.y); float d = pm.y - qm.y;
        kls += (pls - ql.y) - 0.5f + (qs * qs + d * d) * inv2ps2;
        o.y = f2bf(__fmaf_rn(qs, ep.y, qm.y));
      }
      {
        float qs = __expf(ql.z); float d = pm.z - qm.z;
        kls += (pls - ql.z) - 0.5f + (qs * qs + d * d) * inv2ps2;
        o.z = f2bf(__fmaf_rn(qs, ep.z, qm.z));
      }
      {
        float qs = __expf(ql.w); float d = pm.w - qm.w;
        kls += (pls - ql.w) - 0.5f + (qs * qs + d * d) * inv2ps2;
        o.w = f2bf(__fmaf_rn(qs, ep.w, qm.w));
      }
      kl += kls;
      *(ushort4*)(wr + g * 4) = o;
    }
    // tail: col 4096 + zero pad
    if (t == 0) {
      const int c = 4096;
      float qm = q_mu[base + c], ql = q_ls[base + c];
      float qs = __expf(ql);
      float d = p_mu[base + c] - qm;
      kl += (pls - ql) - 0.5f + (qs * qs + d * d) * inv2ps2;
      wr[c] = f2bf(__fmaf_rn(qs, eps[base + c], qm));
    }
    if (t < 31) wr[4097 + t] = 0;
  } else {
#pragma unroll 1
    for (int i = 0; i < 17; ++i) {
      const int c = t + i * 256;
      if (c < 4097) {
        float qm = q_mu[base + c];
        float ql = q_ls[base + c];
        float qs = __expf(ql);
        float e  = eps[base + c];
        float pm = p_mu[base + c];
        float d = pm - qm;
        kl += (pls - ql) - 0.5f + (qs * qs + d * d) * inv2ps2;
        wr[c] = f2bf(__fmaf_rn(qs, e, qm));
      } else if (c < K_PAD) {
        wr[c] = 0;
      }
    }
  }
#pragma unroll
  for (int off = 32; off > 0; off >>= 1) kl += __shfl_down(kl, off, 64);
  __shared__ float part[4];
  const int wave = t >> 6, lane = t & 63;
  if (lane == 0) part[wave] = kl;
  __syncthreads();
  if (t == 0) atomicAdd(kl_out, part[0] + part[1] + part[2] + part[3]);
}

// C(8192x4096 f32) = A(8192xK_PAD bf16) * B^T, B = (4096xK_PAD bf16), both K-contiguous.
// 128x128 tile, BK=32, 4 waves of 64x64, mfma_f32_16x16x32_bf16, global_load_lds staging.
// LDS layout XOR-swizzled: 16B chunk for (row r, kgroup kg) lives at chunk index
// r*4 + (kg ^ ((r>>1)&3)). Staging achieves this by permuting the GLOBAL source
// per lane (LDS dest of global_load_lds is fixed lane-order). Fragment reads then
// hit bank residues {0,4,1,5,2,6,3,7} across rows 0..7 -> 2-way aliasing only (free).
__global__ __launch_bounds__(256) void k_gemm(const unsigned short* __restrict__ A,
                                              const unsigned short* __restrict__ Bm,
                                              float* __restrict__ C) {
  __shared__ unsigned short As[128 * 32];
  __shared__ unsigned short Bs[128 * 32];
  const int t = threadIdx.x;
  const int wave = t >> 6;
  const int lane = t & 63;
  const int wm = wave >> 1;     // 2x2 wave grid
  const int wn = wave & 1;
  const int rowBase = blockIdx.y * 128;
  const int colBase = blockIdx.x * 128;

  const int fr = lane & 15;        // fragment row within 16
  const int kg = lane >> 4;        // k-group (8 bf16 each), 0..3

  f32x4 acc[4][4] = {};

  const unsigned short* Abase = A + (size_t)rowBase * K_PAD;
  const unsigned short* Bbase = Bm + (size_t)colBase * K_PAD;

  // staging: thread t fills LDS chunk c = s*256 + t; chunk holds global
  // (row r = c>>2, kg_src = (c&3) ^ ((r>>1)&3))
  const int r0 = t >> 2;                       // row within tile for s=0 (s adds 64)
  const int kg_src = (t & 3) ^ ((r0 >> 1) & 3);  // (s*64)>>1 is mult of 4 -> no effect
  const int kc = kg_src * 8;                   // k column (bf16) of the 16B chunk

  for (int k0 = 0; k0 < K_PAD; k0 += 32) {
#pragma unroll
    for (int s = 0; s < 2; ++s) {
      const int r = s * 64 + r0;
      const int ldsoff = (s * 256 + wave * 64) * 8;  // wave-uniform base (elements)
      gload_lds16(Abase + (size_t)r * K_PAD + k0 + kc, As + ldsoff);
      gload_lds16(Bbase + (size_t)r * K_PAD + k0 + kc, Bs + ldsoff);
    }
    __syncthreads();
    bf16x8 af[4], bfv[4];
#pragma unroll
    for (int i = 0; i < 4; ++i) {
      const int ra = wm * 64 + i * 16 + fr;
      const int ca = ra * 4 + (kg ^ ((ra >> 1) & 3));   // swizzled chunk index
      af[i]  = *(const bf16x8*)&As[ca * 8];
      const int rb = wn * 64 + i * 16 + fr;
      const int cb = rb * 4 + (kg ^ ((rb >> 1) & 3));
      bfv[i] = *(const bf16x8*)&Bs[cb * 8];
    }
#pragma unroll
    for (int i = 0; i < 4; ++i)
#pragma unroll
      for (int j = 0; j < 4; ++j)
        acc[i][j] = __builtin_amdgcn_mfma_f32_16x16x32_bf16(af[i], bfv[j], acc[i][j], 0, 0, 0);
    __syncthreads();
  }

  // C/D layout: col = lane&15, row = (lane>>4)*4 + reg
  const int cr = (lane >> 4) * 4;
  const int cc = lane & 15;
#pragma unroll
  for (int i = 0; i < 4; ++i) {
#pragma unroll
    for (int j = 0; j < 4; ++j) {
      const int col = colBase + wn * 64 + j * 16 + cc;
#pragma unroll
      for (int r = 0; r < 4; ++r) {
        const int row = rowBase + wm * 64 + i * 16 + cr + r;
        C[(size_t)row * 4096 + col] = acc[i][j][r];
      }
    }
  }
}

extern "C" void kernel_launch(void* const* d_in, const int* in_sizes, int n_in,
                              void* d_out, int out_size, void* d_ws, size_t ws_size,
                              hipStream_t stream) {
  const float* x      = (const float*)d_in[0];
  const float* p_ls   = (const float*)d_in[1];
  const float* q_mu   = (const float*)d_in[2];
  const float* q_lsig = (const float*)d_in[3];
  const float* p_mu   = (const float*)d_in[4];
  const float* eps    = (const float*)d_in[5];
  float* out = (float*)d_out;
  float* kl_out = out + (size_t)8192 * 4096;

  // ws layout: x_aug bf16 (8192*4128 = 67.6MB), weights bf16 (4096*4128 = 33.8MB)
  unsigned short* xa   = (unsigned short*)d_ws;
  unsigned short* wmat = xa + (size_t)8192 * K_PAD;

  hipMemsetAsync(kl_out, 0, sizeof(float), stream);
  k_xaug<<<8192, 256, 0, stream>>>(x, xa);
  k_wkl<<<4096, 256, 0, stream>>>(q_mu, q_lsig, p_mu, eps, p_ls, wmat, kl_out);
  k_gemm<<<dim3(32, 64), 256, 0, stream>>>(xa, wmat, out);
}